// Round 2
// baseline (866.592 us; speedup 1.0000x reference)
//
#include <hip/hip_runtime.h>
#include <stdint.h>

typedef __attribute__((ext_vector_type(8))) __bf16 bf16x8;
typedef __attribute__((ext_vector_type(4))) float f32x4;
typedef __attribute__((ext_vector_type(4))) int i32x4;

#define DEVI static __device__ __forceinline__

constexpr int NN = 2048;   // sequence length
constexpr int DD = 64;     // head dim
constexpr int NH = 16;     // heads
constexpr int NG = 8;      // global heads
constexpr float SCALE = 0.125f;         // 1/sqrt(64)
constexpr float NEGBIG = -1.0e12f;      // MAX_VAL in reference
constexpr size_t OUT_ELEMS = (size_t)2 * NH * NN * DD;      // 4194304
constexpr size_t PG_ELEMS  = (size_t)2 * NG * NN * NN;      // 67108864

struct Frag { bf16x8 hi, lo; };

// fp32 -> (bf16 hi, bf16 lo) split fragment from 8 contiguous floats
DEVI Frag make_frag(const float* p) {
  f32x4 a = *(const f32x4*)p;
  f32x4 b = *(const f32x4*)(p + 4);
  Frag f;
#pragma unroll
  for (int j = 0; j < 8; j++) {
    float x = (j < 4) ? a[j] : b[j - 4];
    __bf16 h = (__bf16)x;
    f.hi[j] = h;
    f.lo[j] = (__bf16)(x - (float)h);
  }
  return f;
}

DEVI f32x4 mfma(bf16x8 a, bf16x8 b, f32x4 c) {
  return __builtin_amdgcn_mfma_f32_16x16x32_bf16(a, b, c, 0, 0, 0);
}

// S^T tile: acc[Mt][r] = S[row = r0+li][col = wc + Mt*16 + 4*qi + r]
// computed as K · Q^T with hi/lo split (drop lo*lo term).
DEVI void compute_st(const Frag kf[2][2], const Frag qf[2], f32x4 acc[2]) {
#pragma unroll
  for (int Mt = 0; Mt < 2; Mt++) {
    f32x4 c = {0.f, 0.f, 0.f, 0.f};
#pragma unroll
    for (int ks = 0; ks < 2; ks++) {
      c = mfma(kf[Mt][ks].hi, qf[ks].hi, c);
      c = mfma(kf[Mt][ks].hi, qf[ks].lo, c);
      c = mfma(kf[Mt][ks].lo, qf[ks].hi, c);
    }
    acc[Mt] = c;
  }
}

// One job: 16 query rows [r0, r0+16) of head (b, h). LOC => banded local head.
// Every wave runs one global job + one local job => uniform load, no tail.
template <bool LOC>
DEVI void attn_job(int bh, int r0, int lane,
                   const float* __restrict__ Q, const float* __restrict__ K,
                   const float* __restrict__ V, const int* __restrict__ MSK,
                   float* __restrict__ OUT) {
  const int b  = bh >> 3;
  const int hh = bh & 7;
  const int h  = LOC ? (hh + 8) : hh;
  const int qi = lane >> 4;         // quad
  const int li = lane & 15;

  const size_t tb = ((size_t)(b * NH + h) * NN) * DD;
  const float* qp = Q + tb;
  const float* kp = K + tb;
  const float* vp = V + tb;
  const int*   mp = MSK + (size_t)b * NN;
  float* op = OUT + tb;
  float* pp = OUT + OUT_ELEMS + (LOC ? PG_ELEMS : (size_t)0)
                  + ((size_t)(b * NG + hh) * NN) * NN;

  // Q fragments (B-operand of S^T mfma): row r0 + li, 8 consecutive d
  Frag qf[2];
#pragma unroll
  for (int ks = 0; ks < 2; ks++)
    qf[ks] = make_frag(qp + (size_t)(r0 + li) * DD + ks * 32 + qi * 8);

  // band geometry for local heads; cb = 32-aligned first tile col
  int cb = 0;
  if constexpr (LOC) cb = (r0 - 64) & ~31;   // covers [r0-64, r0+80) with 5 tiles

  float m = NEGBIG, l = 0.f;

  // ---------------- Sweep A: online row max + sum (band tiles only) ---------
  const int ntA = LOC ? 5 : 64;
#pragma unroll 1
  for (int t = 0; t < ntA; t++) {
    const int wc = LOC ? (cb + 32 * t) : (32 * t);
    if (LOC && ((unsigned)wc >= (unsigned)NN)) continue;

    Frag kf[2][2];
#pragma unroll
    for (int Mt = 0; Mt < 2; Mt++)
#pragma unroll
      for (int ks = 0; ks < 2; ks++)
        kf[Mt][ks] = make_frag(kp + (size_t)(wc + Mt * 16 + li) * DD + ks * 32 + qi * 8);

    i32x4 mv[2];
    mv[0] = *(const i32x4*)(mp + wc + qi * 4);
    mv[1] = *(const i32x4*)(mp + wc + 16 + qi * 4);

    f32x4 acc[2];
    compute_st(kf, qf, acc);
    const int row = r0 + li;
    float vals[8];
#pragma unroll
    for (int Mt = 0; Mt < 2; Mt++)
#pragma unroll
      for (int r = 0; r < 4; r++) {
        const int col = wc + Mt * 16 + qi * 4 + r;
        bool ok = (mv[Mt][r] != 0);
        if constexpr (LOC) { int d = row - col; if (d < 0) d = -d; ok = ok && (d <= 64); }
        vals[Mt * 4 + r] = ok ? acc[Mt][r] * SCALE : NEGBIG;
      }
    float mx = vals[0];
#pragma unroll
    for (int j = 1; j < 8; j++) mx = fmaxf(mx, vals[j]);
    const float mn = fmaxf(m, mx);
    float s = 0.f;
#pragma unroll
    for (int j = 0; j < 8; j++) s += __expf(vals[j] - mn);
    l = l * __expf(m - mn) + s;
    m = mn;
  }

  // combine partial (m,l) across the 4 quads (lanes differing in bits 4,5)
#pragma unroll
  for (int off = 16; off <= 32; off <<= 1) {
    const float mo  = __shfl_xor(m, off);
    const float lo2 = __shfl_xor(l, off);
    const float mn  = fmaxf(m, mo);
    l = l * __expf(m - mn) + lo2 * __expf(mo - mn);
    m = mn;
  }
  const float rl = 1.0f / l;

  // ---------------- Sweep B: P = softmax, store P, O += P·V ----------------
  f32x4 o[4];
#pragma unroll
  for (int dt = 0; dt < 4; dt++) o[dt] = (f32x4){0.f, 0.f, 0.f, 0.f};

  // shuffle sources: C-layout -> A-layout. target lane (qi,li), col cc=8*qi+j:
  // src quad q' = (2*qi + (j>>2)) & 3, src lane = q'*16 + li, reg = j&3
  const int srcA = (((qi * 2) + 0) & 3) * 16 + li;
  const int srcB = (((qi * 2) + 1) & 3) * 16 + li;
  const bool selB = (qi >> 1) != 0;

  // local: walk ALL 64 tiles; out-of-band tiles store zeros (replaces the
  // separate zero-fill pass — spreads writes through the loop)
#pragma unroll 1
  for (int t = 0; t < 64; t++) {
    const int wc = 32 * t;
    float* prow = pp + (size_t)(r0 + li) * NN + wc + qi * 8;
    if (LOC && ((unsigned)(wc - cb) >= 160u)) {
      const f32x4 z = {0.f, 0.f, 0.f, 0.f};
      *(f32x4*)prow       = z;
      *(f32x4*)(prow + 4) = z;
      continue;
    }

    Frag kf[2][2];
#pragma unroll
    for (int Mt = 0; Mt < 2; Mt++)
#pragma unroll
      for (int ks = 0; ks < 2; ks++)
        kf[Mt][ks] = make_frag(kp + (size_t)(wc + Mt * 16 + li) * DD + ks * 32 + qi * 8);

    i32x4 mv[2];
    mv[0] = *(const i32x4*)(mp + wc + qi * 4);
    mv[1] = *(const i32x4*)(mp + wc + 16 + qi * 4);

    // V fragments (B-operand of PV): vf[dt][j] = V[wc + 8*qi + j][dt*16 + li]
    bf16x8 vf[4];
#pragma unroll
    for (int dt = 0; dt < 4; dt++)
#pragma unroll
      for (int j = 0; j < 8; j++)
        vf[dt][j] = (__bf16)vp[(size_t)(wc + qi * 8 + j) * DD + dt * 16 + li];

    f32x4 acc[2];
    compute_st(kf, qf, acc);
    const int row = r0 + li;
    float pf[8];
#pragma unroll
    for (int Mt = 0; Mt < 2; Mt++)
#pragma unroll
      for (int r = 0; r < 4; r++) {
        const int col = wc + Mt * 16 + qi * 4 + r;
        bool ok = (mv[Mt][r] != 0);
        if constexpr (LOC) { int d = row - col; if (d < 0) d = -d; ok = ok && (d <= 64); }
        const float vv = ok ? acc[Mt][r] * SCALE : NEGBIG;
        pf[Mt * 4 + r] = __expf(vv - m) * rl;
      }
    // C-layout -> A-layout via cross-quad shuffles
    float pa[8];
#pragma unroll
    for (int j = 0; j < 8; j++) {
      const int src = (j < 4) ? srcA : srcB;
      const float v0 = __shfl(pf[0 + (j & 3)], src);
      const float v1 = __shfl(pf[4 + (j & 3)], src);
      pa[j] = selB ? v1 : v0;
    }
    // coalesced P store (row-major, 8 consecutive cols per lane)
    *(f32x4*)prow       = (f32x4){pa[0], pa[1], pa[2], pa[3]};
    *(f32x4*)(prow + 4) = (f32x4){pa[4], pa[5], pa[6], pa[7]};
    // PV accumulate (P already normalized)
    bf16x8 pb;
#pragma unroll
    for (int j = 0; j < 8; j++) pb[j] = (__bf16)pa[j];
#pragma unroll
    for (int dt = 0; dt < 4; dt++)
      o[dt] = mfma(pb, vf[dt], o[dt]);
  }

  // epilogue: store O (C-layout: row = qi*4+r, col = li). P already normalized.
#pragma unroll
  for (int dt = 0; dt < 4; dt++)
#pragma unroll
    for (int r = 0; r < 4; r++)
      op[(size_t)(r0 + qi * 4 + r) * DD + dt * 16 + li] = o[dt][r];
}

__global__ __launch_bounds__(256, 2)
void wattn(const float* __restrict__ Q, const float* __restrict__ K,
           const float* __restrict__ V, const int* __restrict__ MSK,
           float* __restrict__ OUT) {
  const int wave = (int)(threadIdx.x >> 6);
  const int lane = (int)(threadIdx.x & 63);
  // bijective XCD swizzle (512 = 8 * 64): each XCD works on 2 consecutive bh
  // => per-XCD L2 working set ~2 MB (K+V for 2 heads) < 4 MB L2
  const int sb = ((int)blockIdx.x & 7) * 64 + ((int)blockIdx.x >> 3);
  const int gw = sb * 4 + wave;      // 0..2047 uniform wave-jobs
  const int bh = gw >> 7;            // 0..15 (b * 8 + head-within-group)
  const int r0 = (gw & 127) * 16;    // 16-row strip

  attn_job<false>(bh, r0, lane, Q, K, V, MSK, OUT);  // global head
  attn_job<true >(bh, r0, lane, Q, K, V, MSK, OUT);  // local (banded) head
}

extern "C" void kernel_launch(void* const* d_in, const int* in_sizes, int n_in,
                              void* d_out, int out_size, void* d_ws, size_t ws_size,
                              hipStream_t stream) {
  (void)in_sizes; (void)n_in; (void)out_size; (void)d_ws; (void)ws_size;
  const float* Q = (const float*)d_in[0];
  const float* K = (const float*)d_in[1];
  const float* V = (const float*)d_in[2];
  const int*   M = (const int*)d_in[3];
  float* O = (float*)d_out;
  wattn<<<dim3(512), dim3(256), 0, stream>>>(Q, K, V, M, O);
}

// Round 3
// 804.883 us; speedup vs baseline: 1.0767x; 1.0767x over previous
//
#include <hip/hip_runtime.h>
#include <stdint.h>

typedef __attribute__((ext_vector_type(8))) __bf16 bf16x8;
typedef __attribute__((ext_vector_type(4))) float f32x4;
typedef __attribute__((ext_vector_type(4))) int i32x4;

#define DEVI static __device__ __forceinline__

constexpr int NN = 2048;   // sequence length
constexpr int DD = 64;     // head dim
constexpr int NH = 16;     // heads
constexpr int NG = 8;      // global heads
constexpr float SCALE = 0.125f;         // 1/sqrt(64)
constexpr float NEGBIG = -1.0e12f;      // MAX_VAL in reference
constexpr size_t OUT_ELEMS = (size_t)2 * NH * NN * DD;      // 4194304
constexpr size_t PG_ELEMS  = (size_t)2 * NG * NN * NN;      // 67108864
constexpr size_t T_ELEMS   = (size_t)2 * NH * NN * DD;      // per tensor
// ws layout (bf16): Qhi | Qlo | Khi | Klo | Vt([bh][d][n])
constexpr size_t WS_NEED   = 5 * T_ELEMS * sizeof(__bf16);  // ~40 MiB

struct Frag { bf16x8 hi, lo; };

// fp32 -> (bf16 hi, bf16 lo) split fragment from 8 contiguous floats
DEVI Frag make_frag(const float* p) {
  f32x4 a = *(const f32x4*)p;
  f32x4 b = *(const f32x4*)(p + 4);
  Frag f;
#pragma unroll
  for (int j = 0; j < 8; j++) {
    float x = (j < 4) ? a[j] : b[j - 4];
    __bf16 h = (__bf16)x;
    f.hi[j] = h;
    f.lo[j] = (__bf16)(x - (float)h);
  }
  return f;
}

DEVI f32x4 mfma(bf16x8 a, bf16x8 b, f32x4 c) {
  return __builtin_amdgcn_mfma_f32_16x16x32_bf16(a, b, c, 0, 0, 0);
}

// K tile (32 cols) fragments + mask words — the double-buffered unit
struct KT { bf16x8 hi[2][2]; bf16x8 lo[2][2]; i32x4 mv[2]; };
// V tile fragments for PV
struct VT { bf16x8 v[4]; };

template <bool PRE>
DEVI void load_kt(KT& kt, const __bf16* khi, const __bf16* klo,
                  const float* kp, const int* mp, int wc, int li, int qi) {
#pragma unroll
  for (int Mt = 0; Mt < 2; Mt++)
#pragma unroll
    for (int ks = 0; ks < 2; ks++) {
      const size_t off = (size_t)(wc + Mt * 16 + li) * DD + ks * 32 + qi * 8;
      if constexpr (PRE) {
        kt.hi[Mt][ks] = *(const bf16x8*)(khi + off);
        kt.lo[Mt][ks] = *(const bf16x8*)(klo + off);
      } else {
        Frag f = make_frag(kp + off);
        kt.hi[Mt][ks] = f.hi;
        kt.lo[Mt][ks] = f.lo;
      }
    }
  kt.mv[0] = *(const i32x4*)(mp + wc + qi * 4);
  kt.mv[1] = *(const i32x4*)(mp + wc + 16 + qi * 4);
}

template <bool PRE>
DEVI void load_vt(VT& vt, const __bf16* vtp, const float* vp, int wc, int li, int qi) {
  if constexpr (PRE) {
#pragma unroll
    for (int dt = 0; dt < 4; dt++)
      vt.v[dt] = *(const bf16x8*)(vtp + (size_t)(dt * 16 + li) * NN + wc + qi * 8);
  } else {
#pragma unroll
    for (int dt = 0; dt < 4; dt++)
#pragma unroll
      for (int j = 0; j < 8; j++)
        vt.v[dt][j] = (__bf16)vp[(size_t)(wc + qi * 8 + j) * DD + dt * 16 + li];
  }
}

// ---- sweep A tile: online row max + sum for both rs slices ----
template <bool LOC>
DEVI void tileA(const KT& kt, const Frag qf[2][2], int wc, int rb, int li, int qi,
                float* m, float* l) {
#pragma unroll
  for (int rs = 0; rs < 2; rs++) {
    f32x4 acc[2];
#pragma unroll
    for (int Mt = 0; Mt < 2; Mt++) {
      f32x4 c = {0.f, 0.f, 0.f, 0.f};
#pragma unroll
      for (int ks = 0; ks < 2; ks++) {
        c = mfma(kt.hi[Mt][ks], qf[rs][ks].hi, c);
        c = mfma(kt.hi[Mt][ks], qf[rs][ks].lo, c);
        c = mfma(kt.lo[Mt][ks], qf[rs][ks].hi, c);
      }
      acc[Mt] = c;
    }
    const int row = rb + rs * 16 + li;
    float vals[8];
#pragma unroll
    for (int Mt = 0; Mt < 2; Mt++)
#pragma unroll
      for (int r = 0; r < 4; r++) {
        const int col = wc + Mt * 16 + qi * 4 + r;
        bool ok = (kt.mv[Mt][r] != 0);
        if constexpr (LOC) { int d = row - col; if (d < 0) d = -d; ok = ok && (d <= 64); }
        vals[Mt * 4 + r] = ok ? acc[Mt][r] * SCALE : NEGBIG;
      }
    float mx = vals[0];
#pragma unroll
    for (int j = 1; j < 8; j++) mx = fmaxf(mx, vals[j]);
    const float mn = fmaxf(m[rs], mx);
    float s = 0.f;
#pragma unroll
    for (int j = 0; j < 8; j++) s += __expf(vals[j] - mn);
    l[rs] = l[rs] * __expf(m[rs] - mn) + s;
    m[rs] = mn;
  }
}

// ---- sweep B tile: P = softmax, store P, O += P·V, both rs slices ----
template <bool LOC>
DEVI void tileB(const KT& kt, const VT& vt, const Frag qf[2][2], int wc, int rb,
                int li, int qi, const float* m, const float* rl,
                f32x4 (&o)[2][4], float* pp, int srcA, int srcB, bool selB) {
#pragma unroll
  for (int rs = 0; rs < 2; rs++) {
    f32x4 acc[2];
#pragma unroll
    for (int Mt = 0; Mt < 2; Mt++) {
      f32x4 c = {0.f, 0.f, 0.f, 0.f};
#pragma unroll
      for (int ks = 0; ks < 2; ks++) {
        c = mfma(kt.hi[Mt][ks], qf[rs][ks].hi, c);
        c = mfma(kt.hi[Mt][ks], qf[rs][ks].lo, c);
        c = mfma(kt.lo[Mt][ks], qf[rs][ks].hi, c);
      }
      acc[Mt] = c;
    }
    const int row = rb + rs * 16 + li;
    float pf[8];
#pragma unroll
    for (int Mt = 0; Mt < 2; Mt++)
#pragma unroll
      for (int r = 0; r < 4; r++) {
        const int col = wc + Mt * 16 + qi * 4 + r;
        bool ok = (kt.mv[Mt][r] != 0);
        if constexpr (LOC) { int d = row - col; if (d < 0) d = -d; ok = ok && (d <= 64); }
        const float vv = ok ? acc[Mt][r] * SCALE : NEGBIG;
        pf[Mt * 4 + r] = __expf(vv - m[rs]) * rl[rs];
      }
    // C-layout -> A-layout via cross-quad shuffles
    float pa[8];
#pragma unroll
    for (int j = 0; j < 8; j++) {
      const int src = (j < 4) ? srcA : srcB;
      const float v0 = __shfl(pf[0 + (j & 3)], src);
      const float v1 = __shfl(pf[4 + (j & 3)], src);
      pa[j] = selB ? v1 : v0;
    }
    // coalesced P store (row-major, 8 consecutive cols per lane)
    float* prow = pp + (size_t)(rb + rs * 16 + li) * NN + wc + qi * 8;
    *(f32x4*)prow       = (f32x4){pa[0], pa[1], pa[2], pa[3]};
    *(f32x4*)(prow + 4) = (f32x4){pa[4], pa[5], pa[6], pa[7]};
    // PV accumulate (P already normalized)
    bf16x8 pb;
#pragma unroll
    for (int j = 0; j < 8; j++) pb[j] = (__bf16)pa[j];
#pragma unroll
    for (int dt = 0; dt < 4; dt++)
      o[rs][dt] = mfma(pb, vt.v[dt], o[rs][dt]);
  }
}

// One-shot conversion kernel: Q,K -> bf16 hi/lo split; V -> transposed bf16.
// Bit-identical splits to make_frag, so main-kernel numerics are unchanged.
__global__ __launch_bounds__(256)
void prep(const float* __restrict__ Q, const float* __restrict__ K,
          const float* __restrict__ V, __bf16* __restrict__ W) {
  const int bid = blockIdx.x;
  if (bid < 4096) {
    const float* src = (bid < 2048) ? Q : K;
    __bf16* hi = W + ((bid < 2048) ? (size_t)0 : 2 * T_ELEMS);
    __bf16* lo = hi + T_ELEMS;
    const size_t base = ((size_t)(bid & 2047) * 256 + threadIdx.x) * 8;
    f32x4 a = *(const f32x4*)(src + base);
    f32x4 b = *(const f32x4*)(src + base + 4);
    bf16x8 h, l;
#pragma unroll
    for (int j = 0; j < 8; j++) {
      float x = (j < 4) ? a[j] : b[j - 4];
      __bf16 hh = (__bf16)x;
      h[j] = hh;
      l[j] = (__bf16)(x - (float)hh);
    }
    *(bf16x8*)(hi + base) = h;
    *(bf16x8*)(lo + base) = l;
  } else {
    // V transpose: blocks [4096,4608). thread -> (bh, d, 32-col n-group)
    __bf16* vt = W + 4 * T_ELEMS;
    const int t  = (bid - 4096) * 256 + (int)threadIdx.x;
    const int ng = t & 63;
    const int dh = t >> 6;
    const int d  = dh & 63;
    const int bh = dh >> 6;
    const float* vp = V + (size_t)bh * NN * DD;
    __bf16* dst = vt + ((size_t)bh * DD + d) * NN + ng * 32;
    bf16x8 o[4];
#pragma unroll
    for (int j = 0; j < 32; j++)
      o[j >> 3][j & 7] = (__bf16)vp[(size_t)(ng * 32 + j) * DD + d];
#pragma unroll
    for (int k = 0; k < 4; k++) *(bf16x8*)(dst + k * 8) = o[k];
  }
}

template <bool PRE>
__global__ __launch_bounds__(256, 2)
void wattn(const float* __restrict__ Q, const float* __restrict__ K,
           const float* __restrict__ V, const int* __restrict__ MSK,
           float* __restrict__ OUT, const __bf16* __restrict__ W) {
  const int bid = blockIdx.x;
  const bool loc = bid >= 256;
  const int lb = loc ? bid - 256 : bid;
  const int bh = lb >> 4;
  const int b  = bh >> 3;
  const int hh = bh & 7;
  const int h  = loc ? (hh + 8) : hh;
  const int wave = (int)(threadIdx.x >> 6);
  const int lane = (int)(threadIdx.x & 63);
  const int qi = lane >> 4;
  const int li = lane & 15;
  const int rb = (lb & 15) * 128 + wave * 32;  // 32-row strip per wave

  const size_t tb = ((size_t)(b * NH + h) * NN) * DD;
  const float* qp = Q + tb;
  const float* kp = K + tb;
  const float* vp = V + tb;
  const __bf16* qhi = W + tb;
  const __bf16* qlo = W + T_ELEMS + tb;
  const __bf16* khi = W + 2 * T_ELEMS + tb;
  const __bf16* klo = W + 3 * T_ELEMS + tb;
  const __bf16* vtp = W + 4 * T_ELEMS + (size_t)(b * NH + h) * DD * NN;
  const int*   mp = MSK + (size_t)b * NN;
  float* op = OUT + tb;
  float* pp = OUT + OUT_ELEMS + (loc ? PG_ELEMS : (size_t)0)
                  + ((size_t)(b * NG + hh) * NN) * NN;

  // Q fragments: rows rb + rs*16 + li, 8 consecutive d
  Frag qf[2][2];
#pragma unroll
  for (int rs = 0; rs < 2; rs++)
#pragma unroll
    for (int ks = 0; ks < 2; ks++) {
      const size_t off = (size_t)(rb + rs * 16 + li) * DD + ks * 32 + qi * 8;
      if constexpr (PRE) {
        qf[rs][ks].hi = *(const bf16x8*)(qhi + off);
        qf[rs][ks].lo = *(const bf16x8*)(qlo + off);
      } else {
        qf[rs][ks] = make_frag(qp + off);
      }
    }

  float m[2] = {NEGBIG, NEGBIG};
  float l[2] = {0.f, 0.f};

  // ---------------- Sweep A ----------------
  if (!loc) {
    // software-pipelined: prefetch tile t+1 while computing tile t
    KT ka, kb;
    load_kt<PRE>(ka, khi, klo, kp, mp, 0, li, qi);
#pragma unroll 1
    for (int t = 0; t < 64; t += 2) {
      load_kt<PRE>(kb, khi, klo, kp, mp, (t + 1) * 32, li, qi);
      tileA<false>(ka, qf, t * 32, rb, li, qi, m, l);
      const int wn = (t + 2 < 64) ? (t + 2) * 32 : 63 * 32;
      load_kt<PRE>(ka, khi, klo, kp, mp, wn, li, qi);
      tileA<false>(kb, qf, (t + 1) * 32, rb, li, qi, m, l);
    }
  } else {
    // zero-fill p rows outside the band window [wlo, whi)
    int wlo = rb - 64; if (wlo < 0) wlo = 0;
    int whi = rb + 96; if (whi > NN) whi = NN;
    const f32x4 z = {0.f, 0.f, 0.f, 0.f};
#pragma unroll 1
    for (int rr = 0; rr < 32; rr++) {
      float* dst = pp + (size_t)(rb + rr) * NN;
#pragma unroll 1
      for (int c = lane * 4; c < NN; c += 256) {
        if (c >= wlo && c < whi) continue;
        *(f32x4*)(dst + c) = z;
      }
    }
    KT ka;
#pragma unroll 1
    for (int t = 0; t < 5; t++) {
      const int wc = rb - 64 + 32 * t;
      if ((unsigned)wc >= (unsigned)NN) continue;
      load_kt<PRE>(ka, khi, klo, kp, mp, wc, li, qi);
      tileA<true>(ka, qf, wc, rb, li, qi, m, l);
    }
  }

  // combine partial (m,l) across the 4 quads
  float rl[2];
#pragma unroll
  for (int rs = 0; rs < 2; rs++) {
#pragma unroll
    for (int off = 16; off <= 32; off <<= 1) {
      const float mo  = __shfl_xor(m[rs], off);
      const float lo2 = __shfl_xor(l[rs], off);
      const float mn  = fmaxf(m[rs], mo);
      l[rs] = l[rs] * __expf(m[rs] - mn) + lo2 * __expf(mo - mn);
      m[rs] = mn;
    }
    rl[rs] = 1.0f / l[rs];
  }

  // ---------------- Sweep B ----------------
  f32x4 o[2][4];
#pragma unroll
  for (int rs = 0; rs < 2; rs++)
#pragma unroll
    for (int dt = 0; dt < 4; dt++) o[rs][dt] = (f32x4){0.f, 0.f, 0.f, 0.f};

  const int srcA = (((qi * 2) + 0) & 3) * 16 + li;
  const int srcB = (((qi * 2) + 1) & 3) * 16 + li;
  const bool selB = (qi >> 1) != 0;

  if (!loc) {
    KT ka, kb;
    VT va, vb;
    load_kt<PRE>(ka, khi, klo, kp, mp, 0, li, qi);
    load_vt<PRE>(va, vtp, vp, 0, li, qi);
#pragma unroll 1
    for (int t = 0; t < 64; t += 2) {
      load_kt<PRE>(kb, khi, klo, kp, mp, (t + 1) * 32, li, qi);
      load_vt<PRE>(vb, vtp, vp, (t + 1) * 32, li, qi);
      tileB<false>(ka, va, qf, t * 32, rb, li, qi, m, rl, o, pp, srcA, srcB, selB);
      const int wn = (t + 2 < 64) ? (t + 2) * 32 : 63 * 32;
      load_kt<PRE>(ka, khi, klo, kp, mp, wn, li, qi);
      load_vt<PRE>(va, vtp, vp, wn, li, qi);
      tileB<false>(kb, vb, qf, (t + 1) * 32, rb, li, qi, m, rl, o, pp, srcA, srcB, selB);
    }
  } else {
    KT ka;
    VT va;
#pragma unroll 1
    for (int t = 0; t < 5; t++) {
      const int wc = rb - 64 + 32 * t;
      if ((unsigned)wc >= (unsigned)NN) continue;
      load_kt<PRE>(ka, khi, klo, kp, mp, wc, li, qi);
      load_vt<PRE>(va, vtp, vp, wc, li, qi);
      tileB<true>(ka, va, qf, wc, rb, li, qi, m, rl, o, pp, srcA, srcB, selB);
    }
  }

  // epilogue: store O (C-layout: row = qi*4+r, col = li). P already normalized.
#pragma unroll
  for (int rs = 0; rs < 2; rs++)
#pragma unroll
    for (int dt = 0; dt < 4; dt++)
#pragma unroll
      for (int r = 0; r < 4; r++) {
        const int row = rb + rs * 16 + qi * 4 + r;
        op[(size_t)row * DD + dt * 16 + li] = o[rs][dt][r];
      }
}

extern "C" void kernel_launch(void* const* d_in, const int* in_sizes, int n_in,
                              void* d_out, int out_size, void* d_ws, size_t ws_size,
                              hipStream_t stream) {
  (void)in_sizes; (void)n_in; (void)out_size;
  const float* Q = (const float*)d_in[0];
  const float* K = (const float*)d_in[1];
  const float* V = (const float*)d_in[2];
  const int*   M = (const int*)d_in[3];
  float* O = (float*)d_out;
  if (ws_size >= WS_NEED && d_ws != nullptr) {
    __bf16* W = (__bf16*)d_ws;
    prep<<<dim3(4608), dim3(256), 0, stream>>>(Q, K, V, W);
    wattn<true><<<dim3(512), dim3(256), 0, stream>>>(Q, K, V, M, O, W);
  } else {
    wattn<false><<<dim3(512), dim3(256), 0, stream>>>(Q, K, V, M, O, nullptr);
  }
}

// Round 4
// 777.384 us; speedup vs baseline: 1.1148x; 1.0354x over previous
//
#include <hip/hip_runtime.h>
#include <stdint.h>

typedef __attribute__((ext_vector_type(8))) __bf16 bf16x8;
typedef __attribute__((ext_vector_type(4))) float f32x4;
typedef __attribute__((ext_vector_type(4))) int i32x4;

#define DEVI static __device__ __forceinline__

constexpr int NN = 2048;   // sequence length
constexpr int DD = 64;     // head dim
constexpr int NH = 16;     // heads
constexpr int NG = 8;      // global heads
constexpr float SCALE = 0.125f;         // 1/sqrt(64)
constexpr float NEGBIG = -1.0e12f;      // MAX_VAL in reference
constexpr size_t OUT_ELEMS = (size_t)2 * NH * NN * DD;      // 4194304
constexpr size_t PG_ELEMS  = (size_t)2 * NG * NN * NN;      // 67108864
constexpr size_t T_ELEMS   = (size_t)2 * NH * NN * DD;      // per tensor
// ws layout (bf16): Qhi | Qlo | Khi | Klo | Vt([bh][d][n])
constexpr size_t WS_NEED   = 5 * T_ELEMS * sizeof(__bf16);  // ~40 MiB

struct Frag { bf16x8 hi, lo; };

DEVI Frag make_frag(const float* p) {
  f32x4 a = *(const f32x4*)p;
  f32x4 b = *(const f32x4*)(p + 4);
  Frag f;
#pragma unroll
  for (int j = 0; j < 8; j++) {
    float x = (j < 4) ? a[j] : b[j - 4];
    __bf16 h = (__bf16)x;
    f.hi[j] = h;
    f.lo[j] = (__bf16)(x - (float)h);
  }
  return f;
}

DEVI f32x4 mfma(bf16x8 a, bf16x8 b, f32x4 c) {
  return __builtin_amdgcn_mfma_f32_16x16x32_bf16(a, b, c, 0, 0, 0);
}

// K tile (32 cols) fragments + mask words
struct KT { bf16x8 hi[2][2]; bf16x8 lo[2][2]; i32x4 mv[2]; };
struct VT { bf16x8 v[4]; };

template <bool PRE>
DEVI void load_kt(KT& kt, const __bf16* khi, const __bf16* klo,
                  const float* kp, const int* mp, int wc, int li, int qi) {
#pragma unroll
  for (int Mt = 0; Mt < 2; Mt++)
#pragma unroll
    for (int ks = 0; ks < 2; ks++) {
      const size_t off = (size_t)(wc + Mt * 16 + li) * DD + ks * 32 + qi * 8;
      if constexpr (PRE) {
        kt.hi[Mt][ks] = *(const bf16x8*)(khi + off);
        kt.lo[Mt][ks] = *(const bf16x8*)(klo + off);
      } else {
        Frag f = make_frag(kp + off);
        kt.hi[Mt][ks] = f.hi;
        kt.lo[Mt][ks] = f.lo;
      }
    }
  kt.mv[0] = *(const i32x4*)(mp + wc + qi * 4);
  kt.mv[1] = *(const i32x4*)(mp + wc + 16 + qi * 4);
}

template <bool PRE>
DEVI void load_vt(VT& vt, const __bf16* vtp, const float* vp, int wc, int li, int qi) {
  if constexpr (PRE) {
#pragma unroll
    for (int dt = 0; dt < 4; dt++)
      vt.v[dt] = *(const bf16x8*)(vtp + (size_t)(dt * 16 + li) * NN + wc + qi * 8);
  } else {
#pragma unroll
    for (int dt = 0; dt < 4; dt++)
#pragma unroll
      for (int j = 0; j < 8; j++)
        vt.v[dt][j] = (__bf16)vp[(size_t)(wc + qi * 8 + j) * DD + dt * 16 + li];
  }
}

template <bool LOC>
DEVI void tileA(const KT& kt, const Frag qf[2][2], int wc, int rb, int li, int qi,
                float* m, float* l) {
#pragma unroll
  for (int rs = 0; rs < 2; rs++) {
    f32x4 acc[2];
#pragma unroll
    for (int Mt = 0; Mt < 2; Mt++) {
      f32x4 c = {0.f, 0.f, 0.f, 0.f};
#pragma unroll
      for (int ks = 0; ks < 2; ks++) {
        c = mfma(kt.hi[Mt][ks], qf[rs][ks].hi, c);
        c = mfma(kt.hi[Mt][ks], qf[rs][ks].lo, c);
        c = mfma(kt.lo[Mt][ks], qf[rs][ks].hi, c);
      }
      acc[Mt] = c;
    }
    const int row = rb + rs * 16 + li;
    float vals[8];
#pragma unroll
    for (int Mt = 0; Mt < 2; Mt++)
#pragma unroll
      for (int r = 0; r < 4; r++) {
        const int col = wc + Mt * 16 + qi * 4 + r;
        bool ok = (kt.mv[Mt][r] != 0);
        if constexpr (LOC) { int d = row - col; if (d < 0) d = -d; ok = ok && (d <= 64); }
        vals[Mt * 4 + r] = ok ? acc[Mt][r] * SCALE : NEGBIG;
      }
    float mx = vals[0];
#pragma unroll
    for (int j = 1; j < 8; j++) mx = fmaxf(mx, vals[j]);
    const float mn = fmaxf(m[rs], mx);
    float s = 0.f;
#pragma unroll
    for (int j = 0; j < 8; j++) s += __expf(vals[j] - mn);
    l[rs] = l[rs] * __expf(m[rs] - mn) + s;
    m[rs] = mn;
  }
}

template <bool LOC>
DEVI void tileB(const KT& kt, const VT& vt, const Frag qf[2][2], int wc, int rb,
                int li, int qi, const float* m, const float* rl,
                f32x4 (&o)[2][4], float* pp, int srcA, int srcB, bool selB) {
#pragma unroll
  for (int rs = 0; rs < 2; rs++) {
    f32x4 acc[2];
#pragma unroll
    for (int Mt = 0; Mt < 2; Mt++) {
      f32x4 c = {0.f, 0.f, 0.f, 0.f};
#pragma unroll
      for (int ks = 0; ks < 2; ks++) {
        c = mfma(kt.hi[Mt][ks], qf[rs][ks].hi, c);
        c = mfma(kt.hi[Mt][ks], qf[rs][ks].lo, c);
        c = mfma(kt.lo[Mt][ks], qf[rs][ks].hi, c);
      }
      acc[Mt] = c;
    }
    const int row = rb + rs * 16 + li;
    float pf[8];
#pragma unroll
    for (int Mt = 0; Mt < 2; Mt++)
#pragma unroll
      for (int r = 0; r < 4; r++) {
        const int col = wc + Mt * 16 + qi * 4 + r;
        bool ok = (kt.mv[Mt][r] != 0);
        if constexpr (LOC) { int d = row - col; if (d < 0) d = -d; ok = ok && (d <= 64); }
        const float vv = ok ? acc[Mt][r] * SCALE : NEGBIG;
        pf[Mt * 4 + r] = __expf(vv - m[rs]) * rl[rs];
      }
    float pa[8];
#pragma unroll
    for (int j = 0; j < 8; j++) {
      const int src = (j < 4) ? srcA : srcB;
      const float v0 = __shfl(pf[0 + (j & 3)], src);
      const float v1 = __shfl(pf[4 + (j & 3)], src);
      pa[j] = selB ? v1 : v0;
    }
    float* prow = pp + (size_t)(rb + rs * 16 + li) * NN + wc + qi * 8;
    *(f32x4*)prow       = (f32x4){pa[0], pa[1], pa[2], pa[3]};
    *(f32x4*)(prow + 4) = (f32x4){pa[4], pa[5], pa[6], pa[7]};
    bf16x8 pb;
#pragma unroll
    for (int j = 0; j < 8; j++) pb[j] = (__bf16)pa[j];
#pragma unroll
    for (int dt = 0; dt < 4; dt++)
      o[rs][dt] = mfma(pb, vt.v[dt], o[rs][dt]);
  }
}

// One-shot conversion kernel: Q,K -> bf16 hi/lo split; V -> transposed bf16.
__global__ __launch_bounds__(256)
void prep(const float* __restrict__ Q, const float* __restrict__ K,
          const float* __restrict__ V, __bf16* __restrict__ W) {
  const int bid = blockIdx.x;
  if (bid < 4096) {
    const float* src = (bid < 2048) ? Q : K;
    __bf16* hi = W + ((bid < 2048) ? (size_t)0 : 2 * T_ELEMS);
    __bf16* lo = hi + T_ELEMS;
    const size_t base = ((size_t)(bid & 2047) * 256 + threadIdx.x) * 8;
    f32x4 a = *(const f32x4*)(src + base);
    f32x4 b = *(const f32x4*)(src + base + 4);
    bf16x8 h, l;
#pragma unroll
    for (int j = 0; j < 8; j++) {
      float x = (j < 4) ? a[j] : b[j - 4];
      __bf16 hh = (__bf16)x;
      h[j] = hh;
      l[j] = (__bf16)(x - (float)hh);
    }
    *(bf16x8*)(hi + base) = h;
    *(bf16x8*)(lo + base) = l;
  } else {
    __bf16* vt = W + 4 * T_ELEMS;
    const int t  = (bid - 4096) * 256 + (int)threadIdx.x;
    const int ng = t & 63;
    const int dh = t >> 6;
    const int d  = dh & 63;
    const int bh = dh >> 6;
    const float* vp = V + (size_t)bh * NN * DD;
    __bf16* dst = vt + ((size_t)bh * DD + d) * NN + ng * 32;
    bf16x8 o[4];
#pragma unroll
    for (int j = 0; j < 32; j++)
      o[j >> 3][j & 7] = (__bf16)vp[(size_t)(ng * 32 + j) * DD + d];
#pragma unroll
    for (int k = 0; k < 4; k++) *(bf16x8*)(dst + k * 8) = o[k];
  }
}

// Split-K within block: one 32-row strip per block, 4 waves each own a
// quarter of the K-range (16 tiles). (m,l) combined via LDS; O reduced via LDS.
template <bool PRE>
__global__ __launch_bounds__(256, 3)
void wattn(const float* __restrict__ Q, const float* __restrict__ K,
           const float* __restrict__ V, const int* __restrict__ MSK,
           float* __restrict__ OUT, const __bf16* __restrict__ W) {
  __shared__ float2 mlS[4][32];       // [wave][row] partial (m,l)
  __shared__ float  oS[4][32][64];    // 32 KB partial O

  // swizzle: each XCD gets 128 global blocks (2 bh) then 128 local blocks (2 bh);
  // heavy global blocks dispatch first, light local blocks form the tail.
  const int bid0 = (int)blockIdx.x;
  const int xcd = bid0 & 7, jj = bid0 >> 3;
  const int bid = (jj < 128) ? (xcd * 128 + jj) : (1024 + xcd * 128 + (jj - 128));
  const bool loc = bid >= 1024;
  const int lb = loc ? bid - 1024 : bid;
  const int bh = lb >> 6;
  const int b  = bh >> 3;
  const int hh = bh & 7;
  const int h  = loc ? (hh + 8) : hh;
  const int rb = (lb & 63) * 32;      // 32-row strip per BLOCK
  const int wave = (int)(threadIdx.x >> 6);
  const int lane = (int)(threadIdx.x & 63);
  const int qi = lane >> 4;
  const int li = lane & 15;

  const size_t tb = ((size_t)(b * NH + h) * NN) * DD;
  const float* qp = Q + tb;
  const float* kp = K + tb;
  const float* vp = V + tb;
  const __bf16* qhi = W + tb;
  const __bf16* qlo = W + T_ELEMS + tb;
  const __bf16* khi = W + 2 * T_ELEMS + tb;
  const __bf16* klo = W + 3 * T_ELEMS + tb;
  const __bf16* vtp = W + 4 * T_ELEMS + (size_t)(b * NH + h) * DD * NN;
  const int*   mp = MSK + (size_t)b * NN;
  float* op = OUT + tb;
  float* pp = OUT + OUT_ELEMS + (loc ? PG_ELEMS : (size_t)0)
                  + ((size_t)(b * NG + hh) * NN) * NN;

  // local band geometry (strip-level window [wlo, whi), 5 tiles from cb)
  const int cb  = rb - 64;
  const int wlo = cb < 0 ? 0 : cb;
  const int whi = (rb + 96 > NN) ? NN : rb + 96;

  // local: zero-fill P outside the window, all 256 threads, 8-col chunks
  if (loc) {
    const int c0 = (int)threadIdx.x * 8;
    const f32x4 z = {0.f, 0.f, 0.f, 0.f};
#pragma unroll 1
    for (int rr = 0; rr < 32; rr++) {
      if (c0 >= wlo && c0 < whi) continue;   // chunks never straddle (32-aligned bounds)
      float* dst = pp + (size_t)(rb + rr) * NN + c0;
      *(f32x4*)dst       = z;
      *(f32x4*)(dst + 4) = z;
    }
  }

  // Q fragments: rows rb + rs*16 + li (same for all 4 waves; L2 hits)
  Frag qf[2][2];
#pragma unroll
  for (int rs = 0; rs < 2; rs++)
#pragma unroll
    for (int ks = 0; ks < 2; ks++) {
      const size_t off = (size_t)(rb + rs * 16 + li) * DD + ks * 32 + qi * 8;
      if constexpr (PRE) {
        qf[rs][ks].hi = *(const bf16x8*)(qhi + off);
        qf[rs][ks].lo = *(const bf16x8*)(qlo + off);
      } else {
        qf[rs][ks] = make_frag(qp + off);
      }
    }

  float m[2] = {NEGBIG, NEGBIG};
  float l[2] = {0.f, 0.f};

  // ---------------- Sweep A: partial (m,l) over this wave's tiles ----------
  if (!loc) {
#pragma unroll 1
    for (int tt = 0; tt < 16; tt++) {
      const int wc = wave * 512 + tt * 32;
      KT kt;
      load_kt<PRE>(kt, khi, klo, kp, mp, wc, li, qi);
      tileA<false>(kt, qf, wc, rb, li, qi, m, l);
    }
  } else {
#pragma unroll 1
    for (int t = wave; t < 5; t += 4) {
      const int wc = cb + 32 * t;
      if ((unsigned)wc >= (unsigned)NN) continue;
      KT kt;
      load_kt<PRE>(kt, khi, klo, kp, mp, wc, li, qi);
      tileA<true>(kt, qf, wc, rb, li, qi, m, l);
    }
  }

  // quad combine within wave (lanes differing in bits 4,5)
#pragma unroll
  for (int rs = 0; rs < 2; rs++) {
#pragma unroll
    for (int off = 16; off <= 32; off <<= 1) {
      const float mo  = __shfl_xor(m[rs], off);
      const float lo2 = __shfl_xor(l[rs], off);
      const float mn  = fmaxf(m[rs], mo);
      l[rs] = l[rs] * __expf(m[rs] - mn) + lo2 * __expf(mo - mn);
      m[rs] = mn;
    }
    if (qi == 0) mlS[wave][rs * 16 + li] = make_float2(m[rs], l[rs]);
  }
  __syncthreads();

  // cross-wave combine (fixed order w=0..3 => deterministic)
  float rl[2];
#pragma unroll
  for (int rs = 0; rs < 2; rs++) {
    float mm = NEGBIG, ll = 0.f;
#pragma unroll
    for (int w = 0; w < 4; w++) {
      const float2 p = mlS[w][rs * 16 + li];
      const float mn = fmaxf(mm, p.x);
      ll = ll * __expf(mm - mn) + p.y * __expf(p.x - mn);
      mm = mn;
    }
    m[rs] = mm;
    rl[rs] = 1.0f / ll;
  }

  // ---------------- Sweep B: P + partial O over this wave's tiles ----------
  f32x4 o[2][4];
#pragma unroll
  for (int rs = 0; rs < 2; rs++)
#pragma unroll
    for (int dt = 0; dt < 4; dt++) o[rs][dt] = (f32x4){0.f, 0.f, 0.f, 0.f};

  const int srcA = (((qi * 2) + 0) & 3) * 16 + li;
  const int srcB = (((qi * 2) + 1) & 3) * 16 + li;
  const bool selB = (qi >> 1) != 0;

  if (!loc) {
#pragma unroll 1
    for (int tt = 0; tt < 16; tt++) {
      const int wc = wave * 512 + tt * 32;
      KT kt;
      VT vt;
      load_kt<PRE>(kt, khi, klo, kp, mp, wc, li, qi);
      load_vt<PRE>(vt, vtp, vp, wc, li, qi);
      tileB<false>(kt, vt, qf, wc, rb, li, qi, m, rl, o, pp, srcA, srcB, selB);
    }
  } else {
#pragma unroll 1
    for (int t = wave; t < 5; t += 4) {
      const int wc = cb + 32 * t;
      if ((unsigned)wc >= (unsigned)NN) continue;
      KT kt;
      VT vt;
      load_kt<PRE>(kt, khi, klo, kp, mp, wc, li, qi);
      load_vt<PRE>(vt, vtp, vp, wc, li, qi);
      tileB<true>(kt, vt, qf, wc, rb, li, qi, m, rl, o, pp, srcA, srcB, selB);
    }
  }

  // ---------------- O reduction across waves via LDS ----------------
#pragma unroll
  for (int rs = 0; rs < 2; rs++)
#pragma unroll
    for (int dt = 0; dt < 4; dt++)
#pragma unroll
      for (int r = 0; r < 4; r++)
        oS[wave][rs * 16 + qi * 4 + r][dt * 16 + li] = o[rs][dt][r];
  __syncthreads();

  const int tid = (int)threadIdx.x;
  const int rr = tid >> 3;
  const int d0 = (tid & 7) * 8;
  f32x4 s0 = {0.f, 0.f, 0.f, 0.f};
  f32x4 s1 = {0.f, 0.f, 0.f, 0.f};
#pragma unroll
  for (int w = 0; w < 4; w++) {      // fixed order => deterministic
    const float* qq = &oS[w][rr][d0];
    s0 += *(const f32x4*)qq;
    s1 += *(const f32x4*)(qq + 4);
  }
  *(f32x4*)(op + (size_t)(rb + rr) * DD + d0)     = s0;
  *(f32x4*)(op + (size_t)(rb + rr) * DD + d0 + 4) = s1;
}

extern "C" void kernel_launch(void* const* d_in, const int* in_sizes, int n_in,
                              void* d_out, int out_size, void* d_ws, size_t ws_size,
                              hipStream_t stream) {
  (void)in_sizes; (void)n_in; (void)out_size;
  const float* Q = (const float*)d_in[0];
  const float* K = (const float*)d_in[1];
  const float* V = (const float*)d_in[2];
  const int*   M = (const int*)d_in[3];
  float* O = (float*)d_out;
  if (ws_size >= WS_NEED && d_ws != nullptr) {
    __bf16* W = (__bf16*)d_ws;
    prep<<<dim3(4608), dim3(256), 0, stream>>>(Q, K, V, W);
    wattn<true><<<dim3(2048), dim3(256), 0, stream>>>(Q, K, V, M, O, W);
  } else {
    wattn<false><<<dim3(2048), dim3(256), 0, stream>>>(Q, K, V, M, O, nullptr);
  }
}